// Round 3
// baseline (1762.948 us; speedup 1.0000x reference)
//
#include <hip/hip_runtime.h>
#include <hip/hip_bf16.h>

#define H 128
constexpr int S1 = 16384, S2 = 4096, S3 = 1024;

typedef unsigned short u16;
typedef float  f32x4 __attribute__((ext_vector_type(4)));
typedef short  s16x8 __attribute__((ext_vector_type(8)));
typedef __bf16 bf16x8 __attribute__((ext_vector_type(8)));

__device__ inline u16 f2bf(float f){
  unsigned u = __builtin_bit_cast(unsigned, f);
  u += 0x7FFFu + ((u >> 16) & 1u);          // RNE
  return (u16)(u >> 16);
}
__device__ inline float bf2f(u16 b){ return __builtin_bit_cast(float, (unsigned)b << 16); }
__device__ inline float ldf(const u16* p, size_t i){ return bf2f(p[i]); }
__device__ inline float ldf(const float* p, size_t i){ return p[i]; }

// build a bf16x8 MFMA fragment (8 consecutive k) from bf16 bits or f32 source
__device__ inline s16x8 ldfrag(const u16* p, int k){
  return *reinterpret_cast<const s16x8*>(p + k);
}
__device__ inline s16x8 ldfrag(const float* p, int k){
  f32x4 f0 = *reinterpret_cast<const f32x4*>(p + k);
  f32x4 f1 = *reinterpret_cast<const f32x4*>(p + k + 4);
  s16x8 r;
  r[0]=(short)f2bf(f0[0]); r[1]=(short)f2bf(f0[1]); r[2]=(short)f2bf(f0[2]); r[3]=(short)f2bf(f0[3]);
  r[4]=(short)f2bf(f1[0]); r[5]=(short)f2bf(f1[1]); r[6]=(short)f2bf(f1[2]); r[7]=(short)f2bf(f1[3]);
  return r;
}
__device__ inline f32x4 mfma16(s16x8 a, s16x8 b, f32x4 c){
  return __builtin_amdgcn_mfma_f32_16x16x32_bf16(
      __builtin_bit_cast(bf16x8, a), __builtin_bit_cast(bf16x8, b), c, 0, 0, 0);
}

// -------------------- edge GNN: e_up = LN(silu([feat|send[src]|recv[dst]]@W1+b1)@W2+b2)
// aggr[dst] += e_up (atomic); optionally eout = bf16(feat + e_up)
template<typename FT, bool WE>
__global__ __launch_bounds__(256) void edge_gnn(
    const FT* __restrict__ feat,
    const float* __restrict__ send, const float* __restrict__ recv,
    const int* __restrict__ src, const int* __restrict__ dst,
    const u16* __restrict__ W1T, const u16* __restrict__ W2T,           // [128][384], [128][128]
    const float* __restrict__ b1, const float* __restrict__ b2,
    const float* __restrict__ lns, const float* __restrict__ lnb,
    float* __restrict__ aggr, u16* __restrict__ eout)
{
  __shared__ u16 h1s[64*128];
  const int tid = threadIdx.x, lane = tid & 63, w = tid >> 6;
  const int l16 = lane & 15, lg = lane >> 4;
  const int eA = blockIdx.x*64 + w*16 + l16;
  const int sA = src[eA], dA = dst[eA];
  const FT* fRow = feat + (size_t)eA*H;
  const float* sRow = send + (size_t)sA*H;
  const float* rRow = recv + (size_t)dA*H;

  f32x4 acc[8];
#pragma unroll
  for(int n=0;n<8;n++) acc[n] = f32x4{0.f,0.f,0.f,0.f};

#pragma unroll
  for(int kk=0; kk<12; kk++){
    const int kq = kk*32 + lg*8;
    const int kl = (kk&3)*32 + lg*8;
    s16x8 a;
    if(kk<4)      a = ldfrag(fRow, kl);
    else if(kk<8) a = ldfrag(sRow, kl);
    else          a = ldfrag(rRow, kl);
#pragma unroll
    for(int n=0;n<8;n++){
      s16x8 b = *reinterpret_cast<const s16x8*>(W1T + (size_t)(n*16+l16)*384 + kq);
      acc[n] = mfma16(a,b,acc[n]);
    }
  }

  const int r0 = w*16 + lg*4;
#pragma unroll
  for(int n=0;n<8;n++){
    const int c = n*16 + l16;
    const float bb = b1[c];
#pragma unroll
    for(int j=0;j<4;j++){
      const int r = r0 + j;
      float x = acc[n][j] + bb;
      float sv = x / (1.f + __expf(-x));
      h1s[r*128 + (((c>>3)^(r&7))<<3) + (c&7)] = f2bf(sv);  // XOR-swizzled (G4)
    }
  }
  __syncthreads();

  f32x4 acc2[8];
#pragma unroll
  for(int n=0;n<8;n++) acc2[n] = f32x4{0.f,0.f,0.f,0.f};
  const int rA = w*16 + l16;
#pragma unroll
  for(int kk=0;kk<4;kk++){
    const int kq = kk*32 + lg*8;
    s16x8 a = *reinterpret_cast<const s16x8*>(&h1s[rA*128 + (((kq>>3)^(rA&7))<<3)]);
#pragma unroll
    for(int n=0;n<8;n++){
      s16x8 b = *reinterpret_cast<const s16x8*>(W2T + (size_t)(n*16+l16)*128 + kq);
      acc2[n] = mfma16(a,b,acc2[n]);
    }
  }

  float hv[8][4];
#pragma unroll
  for(int n=0;n<8;n++){
    const float bb = b2[n*16+l16];
#pragma unroll
    for(int j=0;j<4;j++) hv[n][j] = acc2[n][j] + bb;
  }
  float mj[4], rj[4];
#pragma unroll
  for(int j=0;j<4;j++){
    float s=0.f, q=0.f;
#pragma unroll
    for(int n=0;n<8;n++){ float v=hv[n][j]; s+=v; q+=v*v; }
#pragma unroll
    for(int off=1; off<16; off<<=1){ s += __shfl_xor(s, off); q += __shfl_xor(q, off); }
    const float m = s * (1.f/128.f);
    mj[j] = m;
    float var = q*(1.f/128.f) - m*m;
    rj[j] = rsqrtf((var > 0.f ? var : 0.f) + 1e-5f);
  }
#pragma unroll
  for(int n=0;n<8;n++){
    const int c = n*16+l16;
    const float sc = lns[c];
    const float bo = lnb[c];
#pragma unroll
    for(int j=0;j<4;j++) hv[n][j] = (hv[n][j]-mj[j])*rj[j]*sc + bo;
  }

#pragma unroll
  for(int j=0;j<4;j++){
    const int er = blockIdx.x*64 + r0 + j;
    const int dj = dst[er];
    float* ab = aggr + (size_t)dj*H;
#pragma unroll
    for(int n=0;n<8;n++) atomicAdd(ab + n*16 + l16, hv[n][j]);
    if(WE){
      const size_t eb = (size_t)er*H;
#pragma unroll
      for(int n=0;n<8;n++){
        const int c = n*16+l16;
        eout[eb + c] = f2bf(ldf(feat, eb + c) + hv[n][j]);
      }
    }
  }
}

// -------------------- node GNN: out = recv + LN(silu([recv|aggr]@W1+b1)@W2+b2)
__global__ __launch_bounds__(256) void node_gnn(
    const float* __restrict__ recv, const float* __restrict__ aggr,
    const u16* __restrict__ W1T, const u16* __restrict__ W2T,           // [128][256], [128][128]
    const float* __restrict__ b1, const float* __restrict__ b2,
    const float* __restrict__ lns, const float* __restrict__ lnb,
    float* __restrict__ out)
{
  __shared__ u16 h1s[64*128];
  const int tid = threadIdx.x, lane = tid & 63, w = tid >> 6;
  const int l16 = lane & 15, lg = lane >> 4;
  const int nA = blockIdx.x*64 + w*16 + l16;
  const float* rRow = recv + (size_t)nA*H;
  const float* aRow = aggr + (size_t)nA*H;

  f32x4 acc[8];
#pragma unroll
  for(int n=0;n<8;n++) acc[n] = f32x4{0.f,0.f,0.f,0.f};
#pragma unroll
  for(int kk=0; kk<8; kk++){
    const int kq = kk*32 + lg*8;
    const int kl = (kk&3)*32 + lg*8;
    s16x8 a = (kk<4) ? ldfrag(rRow, kl) : ldfrag(aRow, kl);
#pragma unroll
    for(int n=0;n<8;n++){
      s16x8 b = *reinterpret_cast<const s16x8*>(W1T + (size_t)(n*16+l16)*256 + kq);
      acc[n] = mfma16(a,b,acc[n]);
    }
  }

  const int r0 = w*16 + lg*4;
#pragma unroll
  for(int n=0;n<8;n++){
    const int c = n*16 + l16;
    const float bb = b1[c];
#pragma unroll
    for(int j=0;j<4;j++){
      const int r = r0 + j;
      float x = acc[n][j] + bb;
      float sv = x / (1.f + __expf(-x));
      h1s[r*128 + (((c>>3)^(r&7))<<3) + (c&7)] = f2bf(sv);
    }
  }
  __syncthreads();

  f32x4 acc2[8];
#pragma unroll
  for(int n=0;n<8;n++) acc2[n] = f32x4{0.f,0.f,0.f,0.f};
  const int rA = w*16 + l16;
#pragma unroll
  for(int kk=0;kk<4;kk++){
    const int kq = kk*32 + lg*8;
    s16x8 a = *reinterpret_cast<const s16x8*>(&h1s[rA*128 + (((kq>>3)^(rA&7))<<3)]);
#pragma unroll
    for(int n=0;n<8;n++){
      s16x8 b = *reinterpret_cast<const s16x8*>(W2T + (size_t)(n*16+l16)*128 + kq);
      acc2[n] = mfma16(a,b,acc2[n]);
    }
  }

  float hv[8][4];
#pragma unroll
  for(int n=0;n<8;n++){
    const float bb = b2[n*16+l16];
#pragma unroll
    for(int j=0;j<4;j++) hv[n][j] = acc2[n][j] + bb;
  }
  float mj[4], rj[4];
#pragma unroll
  for(int j=0;j<4;j++){
    float s=0.f, q=0.f;
#pragma unroll
    for(int n=0;n<8;n++){ float v=hv[n][j]; s+=v; q+=v*v; }
#pragma unroll
    for(int off=1; off<16; off<<=1){ s += __shfl_xor(s, off); q += __shfl_xor(q, off); }
    const float m = s * (1.f/128.f);
    mj[j] = m;
    float var = q*(1.f/128.f) - m*m;
    rj[j] = rsqrtf((var > 0.f ? var : 0.f) + 1e-5f);
  }
#pragma unroll
  for(int j=0;j<4;j++){
    const int nr = blockIdx.x*64 + r0 + j;
#pragma unroll
    for(int n=0;n<8;n++){
      const int c = n*16+l16;
      out[(size_t)nr*H + c] = recv[(size_t)nr*H + c] + (hv[n][j]-mj[j])*rj[j]*lns[c] + lnb[c];
    }
  }
}

// -------------------- decoder: params = silu(rep@pW1+pb1)@pW2+pb2; mu/std
__global__ __launch_bounds__(256) void decoder_k(
    const float* __restrict__ rep, const u16* __restrict__ W1T, const u16* __restrict__ W2T,
    const float* __restrict__ b1, const float* __restrict__ b2,
    float* __restrict__ outp)
{
  __shared__ u16 h1s[64*128];
  const int tid = threadIdx.x, lane = tid & 63, w = tid >> 6;
  const int l16 = lane & 15, lg = lane >> 4;
  const int nA = blockIdx.x*64 + w*16 + l16;
  const float* rRow = rep + (size_t)nA*H;

  f32x4 acc[8];
#pragma unroll
  for(int n=0;n<8;n++) acc[n] = f32x4{0.f,0.f,0.f,0.f};
#pragma unroll
  for(int kk=0;kk<4;kk++){
    const int kq = kk*32 + lg*8;
    s16x8 a = ldfrag(rRow, kq);
#pragma unroll
    for(int n=0;n<8;n++){
      s16x8 b = *reinterpret_cast<const s16x8*>(W1T + (size_t)(n*16+l16)*128 + kq);
      acc[n] = mfma16(a,b,acc[n]);
    }
  }
  const int r0 = w*16 + lg*4;
#pragma unroll
  for(int n=0;n<8;n++){
    const int c = n*16 + l16;
    const float bb = b1[c];
#pragma unroll
    for(int j=0;j<4;j++){
      const int r = r0 + j;
      float x = acc[n][j] + bb;
      float sv = x / (1.f + __expf(-x));
      h1s[r*128 + (((c>>3)^(r&7))<<3) + (c&7)] = f2bf(sv);
    }
  }
  __syncthreads();

  f32x4 acc2[4];
#pragma unroll
  for(int n=0;n<4;n++) acc2[n] = f32x4{0.f,0.f,0.f,0.f};
  const int rA = w*16 + l16;
#pragma unroll
  for(int kk=0;kk<4;kk++){
    const int kq = kk*32 + lg*8;
    s16x8 a = *reinterpret_cast<const s16x8*>(&h1s[rA*128 + (((kq>>3)^(rA&7))<<3)]);
#pragma unroll
    for(int n=0;n<4;n++){
      s16x8 b = *reinterpret_cast<const s16x8*>(W2T + (size_t)(n*16+l16)*128 + kq);
      acc2[n] = mfma16(a,b,acc2[n]);
    }
  }
#pragma unroll
  for(int n=0;n<4;n++){
    const int c = n*16 + l16;
    const float bb = b2[c];
#pragma unroll
    for(int j=0;j<4;j++){
      const int row = blockIdx.x*64 + r0 + j;
      float p = acc2[n][j] + bb;
      if(n<2){
        outp[(size_t)row*32 + c] = p;                               // mu
      } else {
        float sp = (p>0.f) ? (p + log1pf(__expf(-p))) : log1pf(__expf(p));
        outp[32768 + (size_t)row*32 + (c-32)] = 1e-4f + sp;         // std
      }
    }
  }
}

// -------------------- small utility kernels
__global__ void transpose_w(const float* __restrict__ in, u16* __restrict__ out, int G, int K, int N){
  long long t = (long long)blockIdx.x*256 + threadIdx.x;
  if(t >= (long long)G*K*N) return;
  int g = (int)(t / ((long long)K*N));
  int r = (int)(t - (long long)g*K*N);
  int k = r / N, n = r - k*N;
  out[(long long)g*N*K + (long long)n*K + k] = f2bf(in[t]);
}
__global__ void add_k(const float* __restrict__ a, const float* __restrict__ b, float* __restrict__ o, int n){
  int i = blockIdx.x*256 + threadIdx.x;
  if(i<n) o[i] = a[i] + b[i];
}
__global__ void copy16(const uint4* __restrict__ in, uint4* __restrict__ out, int n16){
  int i = blockIdx.x*256 + threadIdx.x;
  if(i<n16) out[i] = in[i];
}

// -------------------- host-side orchestration
struct GnnCtx {
  const u16 *eW1T,*eW2T,*nW1T,*nW2T;
  const float *eb1,*eb2,*els,*elb,*nb1,*nb2,*nls,*nlb;
  float* aggr;
  hipStream_t stream;
};

template<typename FT>
static void run_gnn(const GnnCtx& C, int g, const FT* feat,
                    const float* send, const float* recv,
                    const int* src, const int* dst, int E, int Nr, u16* eout, float* nout)
{
  hipMemsetAsync(C.aggr, 0, (size_t)Nr*H*sizeof(float), C.stream);
  const u16* w1 = C.eW1T + (size_t)g*128*384;
  const u16* w2 = C.eW2T + (size_t)g*128*128;
  const u16* v1 = C.nW1T + (size_t)g*128*256;
  const u16* v2 = C.nW2T + (size_t)g*128*128;
  const float *b1=C.eb1+g*H, *b2=C.eb2+g*H, *ls=C.els+g*H, *lb=C.elb+g*H;
  const float *c1=C.nb1+g*H, *c2=C.nb2+g*H, *ms=C.nls+g*H, *mb=C.nlb+g*H;
  if(eout)
    edge_gnn<FT,true ><<<E/64,256,0,C.stream>>>(feat,send,recv,src,dst,w1,w2,b1,b2,ls,lb,C.aggr,eout);
  else
    edge_gnn<FT,false><<<E/64,256,0,C.stream>>>(feat,send,recv,src,dst,w1,w2,b1,b2,ls,lb,C.aggr,nullptr);
  node_gnn<<<Nr/64,256,0,C.stream>>>(recv,C.aggr,v1,v2,c1,c2,ms,mb,nout);
}

extern "C" void kernel_launch(void* const* d_in, const int* in_sizes, int n_in,
                              void* d_out, int out_size, void* d_ws, size_t ws_size,
                              hipStream_t stream) {
  (void)in_sizes; (void)n_in; (void)out_size; (void)ws_size;
  auto fp = [&](int i){ return (const float*)d_in[i]; };
  auto ip = [&](int i){ return (const int*)d_in[i]; };

  const float *highE=fp(0), *lowE=fp(1), *hm1=fp(3), *hm2=fp(4), *lm0=fp(5), *lm1=fp(6);
  const float *hm0=fp(2);

  // workspace carve-up (~70 MB)
  char* cur = (char*)d_ws;
  auto allocF = [&](size_t n){ float* p=(float*)cur; cur += n*sizeof(float); return p; };
  auto allocU = [&](size_t n){ u16* p=(u16*)cur; size_t b = n*2; b = (b+255)&~(size_t)255; cur += b; return p; };

  u16* eW1T = allocU((size_t)15*128*384);
  u16* eW2T = allocU((size_t)15*128*128);
  u16* nW1T = allocU((size_t)15*128*256);
  u16* nW2T = allocU((size_t)15*128*128);
  u16* pW1T = allocU((size_t)128*128);
  u16* pW2T = allocU((size_t)64*128);
  float* aggr = allocF((size_t)S1*H);
  float* RA = allocF((size_t)S1*H);
  float* RB = allocF((size_t)S1*H);
  u16* Ebig = allocU((size_t)131072*H);   // bf16 edge buffers; E1..E4 reuse after the big stage
  u16* E1 = Ebig;
  u16* E2 = Ebig + (size_t)32768*H;
  u16* E3 = Ebig + (size_t)2*32768*H;
  u16* E4 = E3   + (size_t)8192*H;
  float* SA = allocF((size_t)S2*H);
  float* SB = allocF((size_t)S2*H);
  float* SC = allocF((size_t)S2*H);
  float* TA = allocF((size_t)S3*H);
  float* TB = allocF((size_t)S3*H);
  float* TC = allocF((size_t)S3*H);

  // node-state outputs live directly in d_out (f32)
  float* outp = (float*)d_out;
  const size_t O_LOW=65536, O_LIN0=2162688, O_LIN1=2686976, O_LUP0=2818048, O_LUP1=3342336;
  float* L0 = outp + O_LUP0;  // lr_up_rep0
  float* L1 = outp + O_LIN0;  // lr_in0
  float* L2 = outp + O_LUP1;  // lr_up_rep1
  float* L3 = outp + O_LIN1;  // lr_in1

  // weight transposes (f32 -> bf16 bits, [out][in] layout)
  auto T = [&](int idx, u16* out, int G,int K,int N){
    long long tot = (long long)G*K*N;
    transpose_w<<<(unsigned)((tot+255)/256),256,0,stream>>>((const float*)d_in[idx], out, G,K,N);
  };
  T(37, eW1T, 15,384,128);
  T(39, eW2T, 15,128,128);
  T(43, nW1T, 15,256,128);
  T(45, nW2T, 15,128,128);
  T(49, pW1T, 1,128,128);
  T(51, pW2T, 1,128,64);

  GnnCtx C{eW1T,eW2T,nW1T,nW2T,
           fp(38),fp(40),fp(41),fp(42),fp(44),fp(46),fp(47),fp(48),
           aggr, stream};

  // 1. hr_rep = gnn0(high_emb -> hr_mesh0, hr_g2m)              -> RA
  run_gnn(C, 0, fp(7), highE, hm0, ip(8), ip(9), 131072, S1, (u16*)nullptr, RA);
  // 2. _intra(3): hr_m2m0 x2
  run_gnn(C, 3, fp(10), RA, RA, ip(11), ip(12), 131072, S1, Ebig, RB);
  run_gnn(C, 4, (const u16*)Ebig, RB, RB, ip(11), ip(12), 131072, S1, (u16*)nullptr, RA);
  // 3. rep = hr_in + low_emb                                     -> RB
  add_k<<<(S1*H+255)/256,256,0,stream>>>(RA, lowE, RB, S1*H);
  // 4. hr_up = gnn1(send=rep, recv=hr_mesh1, hr_up0)             -> SA
  run_gnn(C, 1, fp(19), RB, hm1, ip(20), ip(21), 65536, S2, (u16*)nullptr, SA);
  // 5. lr_up_rep0 = gnn9(low_emb -> lr_mesh0, lr_g2m)            -> L0
  run_gnn(C, 9, fp(25), lowE, lm0, ip(26), ip(27), 65536, S2, (u16*)nullptr, L0);
  // 6. rep = hr_up + lr_up_rep0                                  -> SB
  add_k<<<(S2*H+255)/256,256,0,stream>>>(SA, L0, SB, S2*H);
  // 7. _intra(5): hr_m2m1 x2                                     -> SA (hr_in)
  run_gnn(C, 5, fp(13), SB, SB, ip(14), ip(15), 32768, S2, E1, SC);
  run_gnn(C, 6, (const u16*)E1, SC, SC, ip(14), ip(15), 32768, S2, (u16*)nullptr, SA);
  // 8. _intra(11): lr_m2m0 x2 on L0                              -> L1 (lr_in0)
  run_gnn(C, 11, fp(28), L0, L0, ip(29), ip(30), 32768, S2, E2, SB);
  run_gnn(C, 12, (const u16*)E2, SB, SB, ip(29), ip(30), 32768, S2, (u16*)nullptr, L1);
  // 9. rep = hr_in + lr_in0                                      -> SC
  add_k<<<(S2*H+255)/256,256,0,stream>>>(SA, L1, SC, S2*H);
  // 10. hr_up = gnn2(send=rep, recv=hr_mesh2, hr_up1)            -> TA
  run_gnn(C, 2, fp(22), SC, hm2, ip(23), ip(24), 16384, S3, (u16*)nullptr, TA);
  // 11. lr_up_rep1 = gnn10(send=lr_in0, recv=lr_mesh1, lr_up0)   -> L2
  run_gnn(C, 10, fp(34), L1, lm1, ip(35), ip(36), 16384, S3, (u16*)nullptr, L2);
  // 12. rep = hr_up + lr_up_rep1                                 -> TB
  add_k<<<(S3*H+255)/256,256,0,stream>>>(TA, L2, TB, S3*H);
  // 13. _intra(7): hr_m2m2 x2                                    -> TA
  run_gnn(C, 7, fp(16), TB, TB, ip(17), ip(18), 8192, S3, E3, TC);
  run_gnn(C, 8, (const u16*)E3, TC, TC, ip(17), ip(18), 8192, S3, (u16*)nullptr, TA);
  // 14. _intra(13): lr_m2m1 x2 on L2                             -> L3 (lr_in1)
  run_gnn(C, 13, fp(31), L2, L2, ip(32), ip(33), 8192, S3, E4, TB);
  run_gnn(C, 14, (const u16*)E4, TB, TB, ip(32), ip(33), 8192, S3, (u16*)nullptr, L3);
  // 15. rep = hr_in + lr_in1                                     -> TC
  add_k<<<(S3*H+255)/256,256,0,stream>>>(TA, L3, TC, S3*H);

  // 16. decoder -> mu/std (f32)
  decoder_k<<<S3/64,256,0,stream>>>(TC, pW1T, pW2T, fp(50), fp(52), outp);

  // 17. low_emb passthrough (f32, 16B vector copy)
  copy16<<<((S1*H/4)+255)/256,256,0,stream>>>((const uint4*)lowE, (uint4*)(outp+O_LOW), S1*H/4);
}